// Round 1
// baseline (3916.870 us; speedup 1.0000x reference)
//
#include <hip/hip_runtime.h>
#include <hip/hip_bf16.h>
#include <math.h>

// ---------------------------------------------------------------------------
// Sizes (fixed for this problem)
// ---------------------------------------------------------------------------
#define R_ROIS 300
#define NCLS 81
#define CBASE 512
#define RCNN_DIN 4096
#define K_FC6 (CBASE * 49)   // 25088
#define FEAT_H 40
#define FEAT_W 40

// ---------------------------------------------------------------------------
// Direct stride-2 3x3 conv, SAME padding (pad_lo=0, pad_hi=1 for even inputs),
// fused bias + relu. Each thread computes COPT consecutive output channels for
// one output pixel. Weight reads are wave-uniform -> scalar loads.
// ---------------------------------------------------------------------------
template <int CIN, int COPT>
__global__ __launch_bounds__(256) void conv_s2_relu(
    const float* __restrict__ in, const float* __restrict__ w,
    const float* __restrict__ bias, float* __restrict__ out,
    int Hin, int Win, int Hout, int Wout) {
  int pix = blockIdx.x * blockDim.x + threadIdx.x;
  int npix = Hout * Wout;
  if (pix >= npix) return;
  int co0 = blockIdx.y * COPT;
  int oy = pix / Wout, ox = pix % Wout;

  float acc[COPT];
#pragma unroll
  for (int j = 0; j < COPT; ++j) acc[j] = bias[co0 + j];

  for (int cin = 0; cin < CIN; ++cin) {
    const float* ip = in + cin * Hin * Win;
    const float* wp = w + (co0 * CIN + cin) * 9;  // + j*CIN*9 + ky*3+kx
#pragma unroll
    for (int ky = 0; ky < 3; ++ky) {
      int iy = oy * 2 + ky;
      if (iy >= Hin) continue;
#pragma unroll
      for (int kx = 0; kx < 3; ++kx) {
        int ix = ox * 2 + kx;
        if (ix >= Win) continue;
        float v = ip[iy * Win + ix];
#pragma unroll
        for (int j = 0; j < COPT; ++j)
          acc[j] = fmaf(v, wp[j * CIN * 9 + ky * 3 + kx], acc[j]);
      }
    }
  }
#pragma unroll
  for (int j = 0; j < COPT; ++j)
    out[(co0 + j) * npix + pix] = fmaxf(acc[j], 0.0f);
}

// ---------------------------------------------------------------------------
// ROI align: out (300, 512, 7, 7); feat (512, 40, 40); SR=2, SCALE=1/16
// ---------------------------------------------------------------------------
__global__ __launch_bounds__(256) void roi_align_kernel(
    const float* __restrict__ feat, const float* __restrict__ rois,
    float* __restrict__ out) {
  int idx = blockIdx.x * blockDim.x + threadIdx.x;
  if (idx >= R_ROIS * CBASE * 49) return;
  int pw = idx % 7;
  int t = idx / 7;
  int ph = t % 7;
  t /= 7;
  int c = t % CBASE;
  int r = t / CBASE;

  const float SCALE = 1.0f / 16.0f;
  float x1 = rois[r * 5 + 1] * SCALE;
  float y1 = rois[r * 5 + 2] * SCALE;
  float x2 = rois[r * 5 + 3] * SCALE;
  float y2 = rois[r * 5 + 4] * SCALE;
  float bw = fmaxf(x2 - x1, 1.0f) * (1.0f / 7.0f);
  float bh = fmaxf(y2 - y1, 1.0f) * (1.0f / 7.0f);

  const float* f = feat + c * FEAT_H * FEAT_W;
  float s = 0.0f;
#pragma unroll
  for (int sy = 0; sy < 2; ++sy) {
    float gy = y1 + ((float)(ph * 2 + sy) + 0.5f) * 0.5f * bh;
    gy = fminf(fmaxf(gy, 0.0f), (float)(FEAT_H - 1));
    int y0 = (int)floorf(gy);
    float wy = gy - (float)y0;
    int y1i = min(y0 + 1, FEAT_H - 1);
#pragma unroll
    for (int sx = 0; sx < 2; ++sx) {
      float gx = x1 + ((float)(pw * 2 + sx) + 0.5f) * 0.5f * bw;
      gx = fminf(fmaxf(gx, 0.0f), (float)(FEAT_W - 1));
      int x0 = (int)floorf(gx);
      float wx = gx - (float)x0;
      int x1i = min(x0 + 1, FEAT_W - 1);
      float v00 = f[y0 * FEAT_W + x0];
      float v01 = f[y0 * FEAT_W + x1i];
      float v10 = f[y1i * FEAT_W + x0];
      float v11 = f[y1i * FEAT_W + x1i];
      s += v00 * (1.0f - wy) * (1.0f - wx) + v01 * (1.0f - wy) * wx +
           v10 * wy * (1.0f - wx) + v11 * wy * wx;
    }
  }
  out[idx] = s * 0.25f;
}

// ---------------------------------------------------------------------------
// Tiled fp32 GEMM: C(M,N) = A(M,K) @ W(N,K)^T + bias, optional relu.
// 64x64 tile, BK=16, 256 threads, 4x4 acc per thread. Guards for ragged M/N.
// K must be a multiple of 16 (holds: 25088, 4096).
// ---------------------------------------------------------------------------
#define TM 64
#define TN 64
#define BK 16
__global__ __launch_bounds__(256) void gemm_nt(
    const float* __restrict__ A, const float* __restrict__ W,
    const float* __restrict__ bias, float* __restrict__ C,
    int M, int N, int K, int relu) {
  __shared__ float As[BK][TM];
  __shared__ float Bs[BK][TN];
  int tid = threadIdx.x;
  int m0 = blockIdx.y * TM;
  int n0 = blockIdx.x * TN;

  int lk = (tid % 4) * 4;  // k offset (float4) within BK
  int lm = tid / 4;        // 0..63 tile row

  int tx = tid % 16, ty = tid / 16;
  float acc[4][4];
#pragma unroll
  for (int i = 0; i < 4; ++i)
#pragma unroll
    for (int j = 0; j < 4; ++j) acc[i][j] = 0.0f;

  for (int kt = 0; kt < K; kt += BK) {
    float4 av = make_float4(0.f, 0.f, 0.f, 0.f);
    if (m0 + lm < M)
      av = *(const float4*)(A + (size_t)(m0 + lm) * K + kt + lk);
    float4 bv = make_float4(0.f, 0.f, 0.f, 0.f);
    if (n0 + lm < N)
      bv = *(const float4*)(W + (size_t)(n0 + lm) * K + kt + lk);

    __syncthreads();
    As[lk + 0][lm] = av.x;
    As[lk + 1][lm] = av.y;
    As[lk + 2][lm] = av.z;
    As[lk + 3][lm] = av.w;
    Bs[lk + 0][lm] = bv.x;
    Bs[lk + 1][lm] = bv.y;
    Bs[lk + 2][lm] = bv.z;
    Bs[lk + 3][lm] = bv.w;
    __syncthreads();

#pragma unroll
    for (int kk = 0; kk < BK; ++kk) {
      float4 a = *(const float4*)&As[kk][ty * 4];
      float4 b = *(const float4*)&Bs[kk][tx * 4];
      acc[0][0] = fmaf(a.x, b.x, acc[0][0]);
      acc[0][1] = fmaf(a.x, b.y, acc[0][1]);
      acc[0][2] = fmaf(a.x, b.z, acc[0][2]);
      acc[0][3] = fmaf(a.x, b.w, acc[0][3]);
      acc[1][0] = fmaf(a.y, b.x, acc[1][0]);
      acc[1][1] = fmaf(a.y, b.y, acc[1][1]);
      acc[1][2] = fmaf(a.y, b.z, acc[1][2]);
      acc[1][3] = fmaf(a.y, b.w, acc[1][3]);
      acc[2][0] = fmaf(a.z, b.x, acc[2][0]);
      acc[2][1] = fmaf(a.z, b.y, acc[2][1]);
      acc[2][2] = fmaf(a.z, b.z, acc[2][2]);
      acc[2][3] = fmaf(a.z, b.w, acc[2][3]);
      acc[3][0] = fmaf(a.w, b.x, acc[3][0]);
      acc[3][1] = fmaf(a.w, b.y, acc[3][1]);
      acc[3][2] = fmaf(a.w, b.z, acc[3][2]);
      acc[3][3] = fmaf(a.w, b.w, acc[3][3]);
    }
  }

#pragma unroll
  for (int i = 0; i < 4; ++i) {
    int m = m0 + ty * 4 + i;
    if (m >= M) continue;
#pragma unroll
    for (int j = 0; j < 4; ++j) {
      int n = n0 + tx * 4 + j;
      if (n >= N) continue;
      float v = acc[i][j] + bias[n];
      if (relu) v = fmaxf(v, 0.0f);
      C[(size_t)m * N + n] = v;
    }
  }
}

// ---------------------------------------------------------------------------
// Softmax over 81 classes, one thread per row (tiny: 300x81)
// ---------------------------------------------------------------------------
__global__ __launch_bounds__(128) void softmax81(const float* __restrict__ in,
                                                 float* __restrict__ out) {
  int r = blockIdx.x * blockDim.x + threadIdx.x;
  if (r >= R_ROIS) return;
  const float* x = in + r * NCLS;
  float m = -1e30f;
  for (int i = 0; i < NCLS; ++i) m = fmaxf(m, x[i]);
  float s = 0.0f;
  for (int i = 0; i < NCLS; ++i) s += expf(x[i] - m);
  float inv = 1.0f / s;
  float* o = out + r * NCLS;
  for (int i = 0; i < NCLS; ++i) o[i] = expf(x[i] - m) * inv;
}

__global__ __launch_bounds__(256) void copy_rois(const float* __restrict__ rois,
                                                 float* __restrict__ out) {
  int i = blockIdx.x * blockDim.x + threadIdx.x;
  if (i < R_ROIS * 5) out[i] = rois[i];
}

// ---------------------------------------------------------------------------
// Launch
// ---------------------------------------------------------------------------
extern "C" void kernel_launch(void* const* d_in, const int* in_sizes, int n_in,
                              void* d_out, int out_size, void* d_ws,
                              size_t ws_size, hipStream_t stream) {
  const float* im = (const float*)d_in[0];
  const float* rois = (const float*)d_in[1];
  const float* w1 = (const float*)d_in[2];
  const float* b1 = (const float*)d_in[3];
  const float* w2 = (const float*)d_in[4];
  const float* b2 = (const float*)d_in[5];
  const float* w3 = (const float*)d_in[6];
  const float* b3 = (const float*)d_in[7];
  const float* w4 = (const float*)d_in[8];
  const float* b4 = (const float*)d_in[9];
  const float* fc6_w = (const float*)d_in[10];
  const float* fc6_b = (const float*)d_in[11];
  const float* fc7_w = (const float*)d_in[12];
  const float* fc7_b = (const float*)d_in[13];
  const float* cls_w = (const float*)d_in[14];
  const float* cls_b = (const float*)d_in[15];
  const float* bbox_w = (const float*)d_in[16];
  const float* bbox_b = (const float*)d_in[17];

  float* ws = (float*)d_ws;
  // buffer plan (floats):
  //   bufA @ 0         : 6,553,600  (x1 = 64x320x320, then x3 = 256x80x80)
  //   bufB @ 6,553,600 : 3,276,800  (x2 = 128x160x160, then x4 = 512x40x40)
  //   pooled @ 9,830,400 : 7,526,400 (300 x 25088)
  //   h6 @ 17,356,800  : 1,228,800
  //   h7 @ 18,585,600  : 1,228,800
  //   cls_score @ 19,814,400 : 24,300
  float* bufA = ws;
  float* bufB = ws + 6553600;
  float* pooled = ws + 9830400;
  float* h6 = ws + 17356800;
  float* h7 = ws + 18585600;
  float* cls_score = ws + 19814400;

  float* out = (float*)d_out;
  float* out_rois = out;            // 1500
  float* out_cls = out + 1500;      // 24300
  float* out_bbox = out + 25800;    // 97200

  // conv1: (3,640,640) -> (64,320,320)
  conv_s2_relu<3, 4><<<dim3(400, 16), 256, 0, stream>>>(im, w1, b1, bufA, 640,
                                                        640, 320, 320);
  // conv2: (64,320,320) -> (128,160,160)
  conv_s2_relu<64, 8><<<dim3(100, 16), 256, 0, stream>>>(bufA, w2, b2, bufB,
                                                         320, 320, 160, 160);
  // conv3: (128,160,160) -> (256,80,80)
  conv_s2_relu<128, 8><<<dim3(25, 32), 256, 0, stream>>>(bufB, w3, b3, bufA,
                                                         160, 160, 80, 80);
  // conv4: (256,80,80) -> (512,40,40)
  conv_s2_relu<256, 8><<<dim3(7, 64), 256, 0, stream>>>(bufA, w4, b4, bufB, 80,
                                                        80, 40, 40);

  // roi align: base_feat = bufB
  roi_align_kernel<<<dim3(29400), 256, 0, stream>>>(bufB, rois, pooled);

  // fc6: (300,25088) @ (4096,25088)^T -> (300,4096), relu
  gemm_nt<<<dim3(64, 5), 256, 0, stream>>>(pooled, fc6_w, fc6_b, h6, R_ROIS,
                                           RCNN_DIN, K_FC6, 1);
  // fc7: (300,4096) @ (4096,4096)^T -> (300,4096), relu
  gemm_nt<<<dim3(64, 5), 256, 0, stream>>>(h6, fc7_w, fc7_b, h7, R_ROIS,
                                           RCNN_DIN, RCNN_DIN, 1);
  // cls: (300,4096) @ (81,4096)^T -> (300,81)
  gemm_nt<<<dim3(2, 5), 256, 0, stream>>>(h7, cls_w, cls_b, cls_score, R_ROIS,
                                          NCLS, RCNN_DIN, 0);
  // bbox: (300,4096) @ (324,4096)^T -> (300,324) directly into out
  gemm_nt<<<dim3(6, 5), 256, 0, stream>>>(h7, bbox_w, bbox_b, out_bbox, R_ROIS,
                                          4 * NCLS, RCNN_DIN, 0);

  // softmax -> out_cls
  softmax81<<<dim3(3), 128, 0, stream>>>(cls_score, out_cls);

  // rois passthrough
  copy_rois<<<dim3(6), 256, 0, stream>>>(rois, out_rois);
}

// Round 2
// 2489.208 us; speedup vs baseline: 1.5735x; 1.5735x over previous
//
#include <hip/hip_runtime.h>
#include <hip/hip_bf16.h>
#include <math.h>

// ---------------------------------------------------------------------------
// Sizes (fixed for this problem)
// ---------------------------------------------------------------------------
#define R_ROIS 300
#define NCLS 81
#define CBASE 512
#define RCNN_DIN 4096
#define K_FC6 (CBASE * 49)   // 25088
#define FEAT_H 40
#define FEAT_W 40

typedef __attribute__((ext_vector_type(8))) short bf16x8;
typedef __attribute__((ext_vector_type(4))) float f32x4;
typedef __attribute__((ext_vector_type(8))) unsigned short ushort8;

// ---------------------------------------------------------------------------
// Direct stride-2 3x3 conv, SAME padding, fused bias + relu.
// ---------------------------------------------------------------------------
template <int CIN, int COPT>
__global__ __launch_bounds__(256) void conv_s2_relu(
    const float* __restrict__ in, const float* __restrict__ w,
    const float* __restrict__ bias, float* __restrict__ out,
    int Hin, int Win, int Hout, int Wout) {
  int pix = blockIdx.x * blockDim.x + threadIdx.x;
  int npix = Hout * Wout;
  if (pix >= npix) return;
  int co0 = blockIdx.y * COPT;
  int oy = pix / Wout, ox = pix % Wout;

  float acc[COPT];
#pragma unroll
  for (int j = 0; j < COPT; ++j) acc[j] = bias[co0 + j];

  for (int cin = 0; cin < CIN; ++cin) {
    const float* ip = in + cin * Hin * Win;
    const float* wp = w + (co0 * CIN + cin) * 9;
#pragma unroll
    for (int ky = 0; ky < 3; ++ky) {
      int iy = oy * 2 + ky;
      if (iy >= Hin) continue;
#pragma unroll
      for (int kx = 0; kx < 3; ++kx) {
        int ix = ox * 2 + kx;
        if (ix >= Win) continue;
        float v = ip[iy * Win + ix];
#pragma unroll
        for (int j = 0; j < COPT; ++j)
          acc[j] = fmaf(v, wp[j * CIN * 9 + ky * 3 + kx], acc[j]);
      }
    }
  }
#pragma unroll
  for (int j = 0; j < COPT; ++j)
    out[(co0 + j) * npix + pix] = fmaxf(acc[j], 0.0f);
}

// ---------------------------------------------------------------------------
// ROI align: out (300, 512, 7, 7); feat (512, 40, 40); SR=2, SCALE=1/16
// ---------------------------------------------------------------------------
__global__ __launch_bounds__(256) void roi_align_kernel(
    const float* __restrict__ feat, const float* __restrict__ rois,
    float* __restrict__ out) {
  int idx = blockIdx.x * blockDim.x + threadIdx.x;
  if (idx >= R_ROIS * CBASE * 49) return;
  int pw = idx % 7;
  int t = idx / 7;
  int ph = t % 7;
  t /= 7;
  int c = t % CBASE;
  int r = t / CBASE;

  const float SCALE = 1.0f / 16.0f;
  float x1 = rois[r * 5 + 1] * SCALE;
  float y1 = rois[r * 5 + 2] * SCALE;
  float x2 = rois[r * 5 + 3] * SCALE;
  float y2 = rois[r * 5 + 4] * SCALE;
  float bw = fmaxf(x2 - x1, 1.0f) * (1.0f / 7.0f);
  float bh = fmaxf(y2 - y1, 1.0f) * (1.0f / 7.0f);

  const float* f = feat + c * FEAT_H * FEAT_W;
  float s = 0.0f;
#pragma unroll
  for (int sy = 0; sy < 2; ++sy) {
    float gy = y1 + ((float)(ph * 2 + sy) + 0.5f) * 0.5f * bh;
    gy = fminf(fmaxf(gy, 0.0f), (float)(FEAT_H - 1));
    int y0 = (int)floorf(gy);
    float wy = gy - (float)y0;
    int y1i = min(y0 + 1, FEAT_H - 1);
#pragma unroll
    for (int sx = 0; sx < 2; ++sx) {
      float gx = x1 + ((float)(pw * 2 + sx) + 0.5f) * 0.5f * bw;
      gx = fminf(fmaxf(gx, 0.0f), (float)(FEAT_W - 1));
      int x0 = (int)floorf(gx);
      float wx = gx - (float)x0;
      int x1i = min(x0 + 1, FEAT_W - 1);
      float v00 = f[y0 * FEAT_W + x0];
      float v01 = f[y0 * FEAT_W + x1i];
      float v10 = f[y1i * FEAT_W + x0];
      float v11 = f[y1i * FEAT_W + x1i];
      s += v00 * (1.0f - wy) * (1.0f - wx) + v01 * (1.0f - wy) * wx +
           v10 * wy * (1.0f - wx) + v11 * wy * wx;
    }
  }
  out[idx] = s * 0.25f;
}

// ---------------------------------------------------------------------------
// bf16-MFMA GEMM: C(M,N) = A(M,K) @ W(N,K)^T + bias, optional relu.
// A, W are fp32 in HBM; staged to LDS as bf16 (RNE), fp32 accumulate in MFMA.
// Block tile 64x64, BK=64, 256 threads (4 waves), wave tile 32x32 via
// 2x2 grid of v_mfma_f32_16x16x32_bf16. LDS row stride 72 bf16 (144 B = 36
// banks -> max 2-way conflict on b128 frag reads, free per m136).
// Requires: N % 64 == 0, K % 64 == 0 (holds for fc6/fc7). M ragged-guarded.
// ---------------------------------------------------------------------------
#define LSTR 72
__global__ __launch_bounds__(256) void gemm_bf16_nt(
    const float* __restrict__ A, const float* __restrict__ W,
    const float* __restrict__ bias, float* __restrict__ C,
    int M, int N, int K, int relu) {
  __shared__ unsigned short As[64 * LSTR];
  __shared__ unsigned short Bs[64 * LSTR];

  int tid = threadIdx.x;
  int m0 = blockIdx.y * 64;
  int n0 = blockIdx.x * 64;

  // staging: thread -> (row, 16-float k-chunk)
  int srow = tid >> 2;
  int skc = (tid & 3) * 16;
  bool aval = (m0 + srow) < M;
  const float* arow = A + (size_t)(m0 + srow) * K + skc;
  const float* brow = W + (size_t)(n0 + srow) * K + skc;
  unsigned short* as_w = As + srow * LSTR + skc;
  unsigned short* bs_w = Bs + srow * LSTR + skc;

  // fragment indexing
  int wave = tid >> 6;
  int lane = tid & 63;
  int wm = (wave >> 1) * 32;
  int wn = (wave & 1) * 32;
  int fm = lane & 15;
  int fk = (lane >> 4) * 8;

  f32x4 acc[2][2];
#pragma unroll
  for (int i = 0; i < 2; ++i)
#pragma unroll
    for (int j = 0; j < 2; ++j) acc[i][j] = (f32x4)(0.0f);

  for (int kt = 0; kt < K; kt += 64) {
    float4 av[4], bv[4];
#pragma unroll
    for (int q = 0; q < 4; ++q) {
      av[q] = aval ? *(const float4*)(arow + kt + q * 4)
                   : make_float4(0.f, 0.f, 0.f, 0.f);
      bv[q] = *(const float4*)(brow + kt + q * 4);
    }
    // convert fp32 -> bf16 (RNE via hip intrinsics -> v_cvt_pk_bf16_f32)
    ushort8 ap[2], bp[2];
#pragma unroll
    for (int h = 0; h < 2; ++h) {
#pragma unroll
      for (int q = 0; q < 2; ++q) {
        float4 a = av[h * 2 + q];
        float4 b = bv[h * 2 + q];
        __hip_bfloat162 a01 = __float22bfloat162_rn(make_float2(a.x, a.y));
        __hip_bfloat162 a23 = __float22bfloat162_rn(make_float2(a.z, a.w));
        __hip_bfloat162 b01 = __float22bfloat162_rn(make_float2(b.x, b.y));
        __hip_bfloat162 b23 = __float22bfloat162_rn(make_float2(b.z, b.w));
        ap[h][q * 4 + 0] = __bfloat16_as_ushort(a01.x);
        ap[h][q * 4 + 1] = __bfloat16_as_ushort(a01.y);
        ap[h][q * 4 + 2] = __bfloat16_as_ushort(a23.x);
        ap[h][q * 4 + 3] = __bfloat16_as_ushort(a23.y);
        bp[h][q * 4 + 0] = __bfloat16_as_ushort(b01.x);
        bp[h][q * 4 + 1] = __bfloat16_as_ushort(b01.y);
        bp[h][q * 4 + 2] = __bfloat16_as_ushort(b23.x);
        bp[h][q * 4 + 3] = __bfloat16_as_ushort(b23.y);
      }
    }

    __syncthreads();  // previous iteration's fragment reads complete
    *(ushort8*)(as_w) = ap[0];
    *(ushort8*)(as_w + 8) = ap[1];
    *(ushort8*)(bs_w) = bp[0];
    *(ushort8*)(bs_w + 8) = bp[1];
    __syncthreads();

#pragma unroll
    for (int kk = 0; kk < 64; kk += 32) {
      bf16x8 af[2], bf[2];
#pragma unroll
      for (int i = 0; i < 2; ++i)
        af[i] = *(const bf16x8*)&As[(wm + i * 16 + fm) * LSTR + kk + fk];
#pragma unroll
      for (int j = 0; j < 2; ++j)
        bf[j] = *(const bf16x8*)&Bs[(wn + j * 16 + fm) * LSTR + kk + fk];
#pragma unroll
      for (int i = 0; i < 2; ++i)
#pragma unroll
        for (int j = 0; j < 2; ++j)
          acc[i][j] = __builtin_amdgcn_mfma_f32_16x16x32_bf16(
              af[i], bf[j], acc[i][j], 0, 0, 0);
    }
  }

  // epilogue: C/D layout col=lane&15, row=(lane>>4)*4+r
  int col = lane & 15;
  int rbase = (lane >> 4) * 4;
#pragma unroll
  for (int i = 0; i < 2; ++i) {
#pragma unroll
    for (int r = 0; r < 4; ++r) {
      int gm = m0 + wm + i * 16 + rbase + r;
      if (gm >= M) continue;
#pragma unroll
      for (int j = 0; j < 2; ++j) {
        int gn = n0 + wn + j * 16 + col;
        float v = acc[i][j][r] + bias[gn];
        if (relu) v = fmaxf(v, 0.0f);
        C[(size_t)gm * N + gn] = v;
      }
    }
  }
}

// ---------------------------------------------------------------------------
// fp32 tiled GEMM (kept for the small heads): C = A @ W^T + bias
// ---------------------------------------------------------------------------
#define TM 64
#define TN 64
#define BK 16
__global__ __launch_bounds__(256) void gemm_nt(
    const float* __restrict__ A, const float* __restrict__ W,
    const float* __restrict__ bias, float* __restrict__ C,
    int M, int N, int K, int relu) {
  __shared__ float As[BK][TM];
  __shared__ float Bs[BK][TN];
  int tid = threadIdx.x;
  int m0 = blockIdx.y * TM;
  int n0 = blockIdx.x * TN;

  int lk = (tid % 4) * 4;
  int lm = tid / 4;

  int tx = tid % 16, ty = tid / 16;
  float acc[4][4];
#pragma unroll
  for (int i = 0; i < 4; ++i)
#pragma unroll
    for (int j = 0; j < 4; ++j) acc[i][j] = 0.0f;

  for (int kt = 0; kt < K; kt += BK) {
    float4 av = make_float4(0.f, 0.f, 0.f, 0.f);
    if (m0 + lm < M)
      av = *(const float4*)(A + (size_t)(m0 + lm) * K + kt + lk);
    float4 bv = make_float4(0.f, 0.f, 0.f, 0.f);
    if (n0 + lm < N)
      bv = *(const float4*)(W + (size_t)(n0 + lm) * K + kt + lk);

    __syncthreads();
    As[lk + 0][lm] = av.x;
    As[lk + 1][lm] = av.y;
    As[lk + 2][lm] = av.z;
    As[lk + 3][lm] = av.w;
    Bs[lk + 0][lm] = bv.x;
    Bs[lk + 1][lm] = bv.y;
    Bs[lk + 2][lm] = bv.z;
    Bs[lk + 3][lm] = bv.w;
    __syncthreads();

#pragma unroll
    for (int kk = 0; kk < BK; ++kk) {
      float4 a = *(const float4*)&As[kk][ty * 4];
      float4 b = *(const float4*)&Bs[kk][tx * 4];
      acc[0][0] = fmaf(a.x, b.x, acc[0][0]);
      acc[0][1] = fmaf(a.x, b.y, acc[0][1]);
      acc[0][2] = fmaf(a.x, b.z, acc[0][2]);
      acc[0][3] = fmaf(a.x, b.w, acc[0][3]);
      acc[1][0] = fmaf(a.y, b.x, acc[1][0]);
      acc[1][1] = fmaf(a.y, b.y, acc[1][1]);
      acc[1][2] = fmaf(a.y, b.z, acc[1][2]);
      acc[1][3] = fmaf(a.y, b.w, acc[1][3]);
      acc[2][0] = fmaf(a.z, b.x, acc[2][0]);
      acc[2][1] = fmaf(a.z, b.y, acc[2][1]);
      acc[2][2] = fmaf(a.z, b.z, acc[2][2]);
      acc[2][3] = fmaf(a.z, b.w, acc[2][3]);
      acc[3][0] = fmaf(a.w, b.x, acc[3][0]);
      acc[3][1] = fmaf(a.w, b.y, acc[3][1]);
      acc[3][2] = fmaf(a.w, b.z, acc[3][2]);
      acc[3][3] = fmaf(a.w, b.w, acc[3][3]);
    }
  }

#pragma unroll
  for (int i = 0; i < 4; ++i) {
    int m = m0 + ty * 4 + i;
    if (m >= M) continue;
#pragma unroll
    for (int j = 0; j < 4; ++j) {
      int n = n0 + tx * 4 + j;
      if (n >= N) continue;
      float v = acc[i][j] + bias[n];
      if (relu) v = fmaxf(v, 0.0f);
      C[(size_t)m * N + n] = v;
    }
  }
}

// ---------------------------------------------------------------------------
// Softmax over 81 classes
// ---------------------------------------------------------------------------
__global__ __launch_bounds__(128) void softmax81(const float* __restrict__ in,
                                                 float* __restrict__ out) {
  int r = blockIdx.x * blockDim.x + threadIdx.x;
  if (r >= R_ROIS) return;
  const float* x = in + r * NCLS;
  float m = -1e30f;
  for (int i = 0; i < NCLS; ++i) m = fmaxf(m, x[i]);
  float s = 0.0f;
  for (int i = 0; i < NCLS; ++i) s += expf(x[i] - m);
  float inv = 1.0f / s;
  float* o = out + r * NCLS;
  for (int i = 0; i < NCLS; ++i) o[i] = expf(x[i] - m) * inv;
}

__global__ __launch_bounds__(256) void copy_rois(const float* __restrict__ rois,
                                                 float* __restrict__ out) {
  int i = blockIdx.x * blockDim.x + threadIdx.x;
  if (i < R_ROIS * 5) out[i] = rois[i];
}

// ---------------------------------------------------------------------------
// Launch
// ---------------------------------------------------------------------------
extern "C" void kernel_launch(void* const* d_in, const int* in_sizes, int n_in,
                              void* d_out, int out_size, void* d_ws,
                              size_t ws_size, hipStream_t stream) {
  const float* im = (const float*)d_in[0];
  const float* rois = (const float*)d_in[1];
  const float* w1 = (const float*)d_in[2];
  const float* b1 = (const float*)d_in[3];
  const float* w2 = (const float*)d_in[4];
  const float* b2 = (const float*)d_in[5];
  const float* w3 = (const float*)d_in[6];
  const float* b3 = (const float*)d_in[7];
  const float* w4 = (const float*)d_in[8];
  const float* b4 = (const float*)d_in[9];
  const float* fc6_w = (const float*)d_in[10];
  const float* fc6_b = (const float*)d_in[11];
  const float* fc7_w = (const float*)d_in[12];
  const float* fc7_b = (const float*)d_in[13];
  const float* cls_w = (const float*)d_in[14];
  const float* cls_b = (const float*)d_in[15];
  const float* bbox_w = (const float*)d_in[16];
  const float* bbox_b = (const float*)d_in[17];

  float* ws = (float*)d_ws;
  float* bufA = ws;                    // 6,553,600
  float* bufB = ws + 6553600;          // 3,276,800
  float* pooled = ws + 9830400;        // 7,526,400 (300 x 25088)
  float* h6 = ws + 17356800;           // 1,228,800
  float* h7 = ws + 18585600;           // 1,228,800
  float* cls_score = ws + 19814400;    // 24,300

  float* out = (float*)d_out;
  float* out_rois = out;
  float* out_cls = out + 1500;
  float* out_bbox = out + 25800;

  conv_s2_relu<3, 4><<<dim3(400, 16), 256, 0, stream>>>(im, w1, b1, bufA, 640,
                                                        640, 320, 320);
  conv_s2_relu<64, 8><<<dim3(100, 16), 256, 0, stream>>>(bufA, w2, b2, bufB,
                                                         320, 320, 160, 160);
  conv_s2_relu<128, 8><<<dim3(25, 32), 256, 0, stream>>>(bufB, w3, b3, bufA,
                                                         160, 160, 80, 80);
  conv_s2_relu<256, 8><<<dim3(7, 64), 256, 0, stream>>>(bufA, w4, b4, bufB, 80,
                                                        80, 40, 40);

  roi_align_kernel<<<dim3(29400), 256, 0, stream>>>(bufB, rois, pooled);

  // fc6: (300,25088) @ (4096,25088)^T, relu  -- bf16 MFMA
  gemm_bf16_nt<<<dim3(64, 5), 256, 0, stream>>>(pooled, fc6_w, fc6_b, h6,
                                                R_ROIS, RCNN_DIN, K_FC6, 1);
  // fc7: (300,4096) @ (4096,4096)^T, relu  -- bf16 MFMA
  gemm_bf16_nt<<<dim3(64, 5), 256, 0, stream>>>(h6, fc7_w, fc7_b, h7, R_ROIS,
                                                RCNN_DIN, RCNN_DIN, 1);
  // heads (small): fp32
  gemm_nt<<<dim3(2, 5), 256, 0, stream>>>(h7, cls_w, cls_b, cls_score, R_ROIS,
                                          NCLS, RCNN_DIN, 0);
  gemm_nt<<<dim3(6, 5), 256, 0, stream>>>(h7, bbox_w, bbox_b, out_bbox, R_ROIS,
                                          4 * NCLS, RCNN_DIN, 0);

  softmax81<<<dim3(3), 128, 0, stream>>>(cls_score, out_cls);
  copy_rois<<<dim3(6), 256, 0, stream>>>(rois, out_rois);
}

// Round 3
// 1339.366 us; speedup vs baseline: 2.9244x; 1.8585x over previous
//
#include <hip/hip_runtime.h>
#include <hip/hip_bf16.h>
#include <math.h>

#define R_ROIS 300
#define NCLS 81
#define RCNN_DIN 4096
#define K_FC6 25088
#define FEAT_H 40
#define FEAT_W 40

typedef __attribute__((ext_vector_type(8))) short bf16x8;
typedef __attribute__((ext_vector_type(4))) float f32x4;
typedef __attribute__((ext_vector_type(8))) unsigned short ushort8;

__device__ inline unsigned short f2bf(float x) {
  union { float f; unsigned u; } v;
  v.f = x;
  unsigned r = v.u + 0x7fff + ((v.u >> 16) & 1);  // RNE
  return (unsigned short)(r >> 16);
}

// ---------------------------------------------------------------------------
// conv1 direct (tiny CIN=3): stride-2 3x3, SAME, bias+relu
// ---------------------------------------------------------------------------
template <int CIN, int COPT>
__global__ __launch_bounds__(256) void conv_s2_relu(
    const float* __restrict__ in, const float* __restrict__ w,
    const float* __restrict__ bias, float* __restrict__ out,
    int Hin, int Win, int Hout, int Wout) {
  int pix = blockIdx.x * blockDim.x + threadIdx.x;
  int npix = Hout * Wout;
  if (pix >= npix) return;
  int co0 = blockIdx.y * COPT;
  int oy = pix / Wout, ox = pix % Wout;

  float acc[COPT];
#pragma unroll
  for (int j = 0; j < COPT; ++j) acc[j] = bias[co0 + j];

  for (int cin = 0; cin < CIN; ++cin) {
    const float* ip = in + cin * Hin * Win;
    const float* wp = w + (co0 * CIN + cin) * 9;
#pragma unroll
    for (int ky = 0; ky < 3; ++ky) {
      int iy = oy * 2 + ky;
      if (iy >= Hin) continue;
#pragma unroll
      for (int kx = 0; kx < 3; ++kx) {
        int ix = ox * 2 + kx;
        if (ix >= Win) continue;
        float v = ip[iy * Win + ix];
#pragma unroll
        for (int j = 0; j < COPT; ++j)
          acc[j] = fmaf(v, wp[j * CIN * 9 + ky * 3 + kx], acc[j]);
      }
    }
  }
#pragma unroll
  for (int j = 0; j < COPT; ++j)
    out[(co0 + j) * npix + pix] = fmaxf(acc[j], 0.0f);
}

// ---------------------------------------------------------------------------
// im2col (stride-2 3x3 SAME), fp32 in -> bf16 col[pix][cin*9+q]
// ---------------------------------------------------------------------------
__global__ __launch_bounds__(256) void im2col_bf16(
    const float* __restrict__ in, unsigned short* __restrict__ col,
    int Cin, int Hin, int Win, int Hout, int Wout) {
  int idx = blockIdx.x * blockDim.x + threadIdx.x;
  int npix = Hout * Wout;
  if (idx >= npix * Cin) return;
  int pix = idx % npix;  // consecutive threads -> consecutive ox (read coalesce)
  int cin = idx / npix;
  int oy = pix / Wout, ox = pix % Wout;
  const float* ip = in + (size_t)cin * Hin * Win;
  unsigned short* cp = col + (size_t)pix * (Cin * 9) + cin * 9;
#pragma unroll
  for (int ky = 0; ky < 3; ++ky) {
    int iy = oy * 2 + ky;
#pragma unroll
    for (int kx = 0; kx < 3; ++kx) {
      int ix = ox * 2 + kx;
      float v = (iy < Hin && ix < Win) ? ip[iy * Win + ix] : 0.0f;
      cp[ky * 3 + kx] = f2bf(v);
    }
  }
}

// ---------------------------------------------------------------------------
// ROI align -> bf16 pooled (300, 512*7*7)
// ---------------------------------------------------------------------------
__global__ __launch_bounds__(256) void roi_align_kernel(
    const float* __restrict__ feat, const float* __restrict__ rois,
    unsigned short* __restrict__ out) {
  int idx = blockIdx.x * blockDim.x + threadIdx.x;
  if (idx >= R_ROIS * 512 * 49) return;
  int pw = idx % 7;
  int t = idx / 7;
  int ph = t % 7;
  t /= 7;
  int c = t % 512;
  int r = t / 512;

  const float SCALE = 1.0f / 16.0f;
  float x1 = rois[r * 5 + 1] * SCALE;
  float y1 = rois[r * 5 + 2] * SCALE;
  float x2 = rois[r * 5 + 3] * SCALE;
  float y2 = rois[r * 5 + 4] * SCALE;
  float bw = fmaxf(x2 - x1, 1.0f) * (1.0f / 7.0f);
  float bh = fmaxf(y2 - y1, 1.0f) * (1.0f / 7.0f);

  const float* f = feat + c * FEAT_H * FEAT_W;
  float s = 0.0f;
#pragma unroll
  for (int sy = 0; sy < 2; ++sy) {
    float gy = y1 + ((float)(ph * 2 + sy) + 0.5f) * 0.5f * bh;
    gy = fminf(fmaxf(gy, 0.0f), (float)(FEAT_H - 1));
    int y0 = (int)floorf(gy);
    float wy = gy - (float)y0;
    int y1i = min(y0 + 1, FEAT_H - 1);
#pragma unroll
    for (int sx = 0; sx < 2; ++sx) {
      float gx = x1 + ((float)(pw * 2 + sx) + 0.5f) * 0.5f * bw;
      gx = fminf(fmaxf(gx, 0.0f), (float)(FEAT_W - 1));
      int x0 = (int)floorf(gx);
      float wx = gx - (float)x0;
      int x1i = min(x0 + 1, FEAT_W - 1);
      float v00 = f[y0 * FEAT_W + x0];
      float v01 = f[y0 * FEAT_W + x1i];
      float v10 = f[y1i * FEAT_W + x0];
      float v11 = f[y1i * FEAT_W + x1i];
      s += v00 * (1.0f - wy) * (1.0f - wx) + v01 * (1.0f - wy) * wx +
           v10 * wy * (1.0f - wx) + v11 * wy * wx;
    }
  }
  out[idx] = f2bf(s * 0.25f);
}

// ---------------------------------------------------------------------------
// Generic MFMA GEMM: Cpart[s] (M,N) = A(M,K) @ B(N,K)^T over k-range s.
// A/B fp32 or bf16 in HBM; LDS bf16; 128x128 tile, BK=64, 256 thr (4 waves,
// wave tile 64x64 = 4x4 of 16x16x32). Register double-buffer prefetch of the
// next K-slab overlaps global latency with the MFMA loop. LDS rows padded to
// 72 bf16 (2-way bank alias max = free). grid = (N/128, ceil(M/128), S),
// Ksplit = Kfull / S, Ksplit % 64 == 0. No bias/act here (finalize does it).
// ---------------------------------------------------------------------------
union RawT {
  float4 f[8];   // fp32 source: 32 floats
  ushort8 h[8];  // bf16 source: h[0..3] = 32 bf16
};

__device__ inline void load_f32(const float* p, bool valid, RawT& r) {
#pragma unroll
  for (int q = 0; q < 8; ++q)
    r.f[q] = valid ? *(const float4*)(p + q * 4) : make_float4(0.f, 0.f, 0.f, 0.f);
}
__device__ inline void load_b16(const unsigned short* p, bool valid, RawT& r) {
#pragma unroll
  for (int q = 0; q < 4; ++q) {
    if (valid)
      r.h[q] = *(const ushort8*)(p + q * 8);
    else
      r.h[q] = (ushort8)0;
  }
}
__device__ inline void cvt_f32(const RawT& r, ushort8 pk[4]) {
#pragma unroll
  for (int q = 0; q < 4; ++q) {
    float4 a = r.f[2 * q], b = r.f[2 * q + 1];
    __hip_bfloat162 p0 = __float22bfloat162_rn(make_float2(a.x, a.y));
    __hip_bfloat162 p1 = __float22bfloat162_rn(make_float2(a.z, a.w));
    __hip_bfloat162 p2 = __float22bfloat162_rn(make_float2(b.x, b.y));
    __hip_bfloat162 p3 = __float22bfloat162_rn(make_float2(b.z, b.w));
    pk[q][0] = __bfloat16_as_ushort(p0.x);
    pk[q][1] = __bfloat16_as_ushort(p0.y);
    pk[q][2] = __bfloat16_as_ushort(p1.x);
    pk[q][3] = __bfloat16_as_ushort(p1.y);
    pk[q][4] = __bfloat16_as_ushort(p2.x);
    pk[q][5] = __bfloat16_as_ushort(p2.y);
    pk[q][6] = __bfloat16_as_ushort(p3.x);
    pk[q][7] = __bfloat16_as_ushort(p3.y);
  }
}

#define LSTR 72
template <bool ABF16, bool BBF16>
__global__ __launch_bounds__(256) void gemm_mfma(
    const void* __restrict__ Ap, const void* __restrict__ Bp,
    float* __restrict__ Cpart, int M, int N, int Kfull, int Ksplit) {
  __shared__ unsigned short As[128 * LSTR];
  __shared__ unsigned short Bs[128 * LSTR];
  const int tid = threadIdx.x;
  const int m0 = blockIdx.y * 128;
  const int n0 = blockIdx.x * 128;
  const int s = blockIdx.z;
  const int k0 = s * Ksplit;

  const int srow = tid >> 1;          // 0..127
  const int scol = (tid & 1) * 32;    // 0 or 32
  const bool avalid = (m0 + srow) < M;
  const bool bvalid = (n0 + srow) < N;

  const float* Af = (const float*)Ap + (size_t)(m0 + srow) * Kfull + k0 + scol;
  const unsigned short* Ab =
      (const unsigned short*)Ap + (size_t)(m0 + srow) * Kfull + k0 + scol;
  const float* Bf = (const float*)Bp + (size_t)(n0 + srow) * Kfull + k0 + scol;
  const unsigned short* Bb =
      (const unsigned short*)Bp + (size_t)(n0 + srow) * Kfull + k0 + scol;

  const int wave = tid >> 6;
  const int lane = tid & 63;
  const int wm = (wave >> 1) * 64;
  const int wn = (wave & 1) * 64;
  const int fm = lane & 15;
  const int fk = (lane >> 4) * 8;

  f32x4 acc[4][4];
#pragma unroll
  for (int i = 0; i < 4; ++i)
#pragma unroll
    for (int j = 0; j < 4; ++j) acc[i][j] = (f32x4)(0.0f);

  RawT ra, rb;
  if (ABF16) load_b16(Ab, avalid, ra); else load_f32(Af, avalid, ra);
  if (BBF16) load_b16(Bb, bvalid, rb); else load_f32(Bf, bvalid, rb);
  RawT na = ra, nb = rb;

  for (int kt = 0; kt < Ksplit; kt += 64) {
    int ktn = kt + 64;
    if (ktn < Ksplit) {  // prefetch next slab (overlaps MFMA below)
      if (ABF16) load_b16(Ab + ktn, avalid, na); else load_f32(Af + ktn, avalid, na);
      if (BBF16) load_b16(Bb + ktn, bvalid, nb); else load_f32(Bf + ktn, bvalid, nb);
    }
    ushort8 pa[4], pb[4];
    if (ABF16) {
#pragma unroll
      for (int q = 0; q < 4; ++q) pa[q] = ra.h[q];
    } else
      cvt_f32(ra, pa);
    if (BBF16) {
#pragma unroll
      for (int q = 0; q < 4; ++q) pb[q] = rb.h[q];
    } else
      cvt_f32(rb, pb);

    __syncthreads();
    unsigned short* aw = &As[srow * LSTR + scol];
    unsigned short* bw = &Bs[srow * LSTR + scol];
    *(ushort8*)(aw) = pa[0];
    *(ushort8*)(aw + 8) = pa[1];
    *(ushort8*)(aw + 16) = pa[2];
    *(ushort8*)(aw + 24) = pa[3];
    *(ushort8*)(bw) = pb[0];
    *(ushort8*)(bw + 8) = pb[1];
    *(ushort8*)(bw + 16) = pb[2];
    *(ushort8*)(bw + 24) = pb[3];
    __syncthreads();

#pragma unroll
    for (int kk = 0; kk < 64; kk += 32) {
      bf16x8 af[4], bfr[4];
#pragma unroll
      for (int i = 0; i < 4; ++i)
        af[i] = *(const bf16x8*)&As[(wm + i * 16 + fm) * LSTR + kk + fk];
#pragma unroll
      for (int j = 0; j < 4; ++j)
        bfr[j] = *(const bf16x8*)&Bs[(wn + j * 16 + fm) * LSTR + kk + fk];
#pragma unroll
      for (int i = 0; i < 4; ++i)
#pragma unroll
        for (int j = 0; j < 4; ++j)
          acc[i][j] = __builtin_amdgcn_mfma_f32_16x16x32_bf16(af[i], bfr[j],
                                                              acc[i][j], 0, 0, 0);
    }
    ra = na;
    rb = nb;
  }

  // epilogue: C/D layout col=lane&15, row=(lane>>4)*4+r
  const int col = lane & 15;
  const int rb4 = (lane >> 4) * 4;
  float* Cp = Cpart + (size_t)s * M * N;
#pragma unroll
  for (int i = 0; i < 4; ++i) {
#pragma unroll
    for (int r = 0; r < 4; ++r) {
      int gm = m0 + wm + i * 16 + rb4 + r;
      if (gm >= M) continue;
#pragma unroll
      for (int j = 0; j < 4; ++j) {
        int gn = n0 + wn + j * 16 + col;
        if (gn < N) Cp[(size_t)gm * N + gn] = acc[i][j][r];
      }
    }
  }
}

// ---------------------------------------------------------------------------
// finalize: out = act(sum_s part[s] + bias[axis]) ; fp32 or bf16 out
// ---------------------------------------------------------------------------
__global__ __launch_bounds__(256) void finalize_kernel(
    const float* __restrict__ part, const float* __restrict__ bias,
    void* __restrict__ out, int M, int N, int S, int bias_on_n, int relu,
    int out_bf16) {
  int idx = blockIdx.x * blockDim.x + threadIdx.x;
  if (idx >= M * N) return;
  int m = idx / N;
  int n = idx - m * N;
  float v = 0.0f;
  for (int s2 = 0; s2 < S; ++s2) v += part[(size_t)s2 * M * N + idx];
  v += bias[bias_on_n ? n : m];
  if (relu) v = fmaxf(v, 0.0f);
  if (out_bf16)
    ((unsigned short*)out)[idx] = f2bf(v);
  else
    ((float*)out)[idx] = v;
}

// ---------------------------------------------------------------------------
// softmax over 81 classes; rois passthrough
// ---------------------------------------------------------------------------
__global__ __launch_bounds__(128) void softmax81(const float* __restrict__ in,
                                                 float* __restrict__ out) {
  int r = blockIdx.x * blockDim.x + threadIdx.x;
  if (r >= R_ROIS) return;
  const float* x = in + r * NCLS;
  float m = -1e30f;
  for (int i = 0; i < NCLS; ++i) m = fmaxf(m, x[i]);
  float s = 0.0f;
  for (int i = 0; i < NCLS; ++i) s += expf(x[i] - m);
  float inv = 1.0f / s;
  float* o = out + r * NCLS;
  for (int i = 0; i < NCLS; ++i) o[i] = expf(x[i] - m) * inv;
}

__global__ __launch_bounds__(256) void copy_rois(const float* __restrict__ rois,
                                                 float* __restrict__ out) {
  int i = blockIdx.x * blockDim.x + threadIdx.x;
  if (i < R_ROIS * 5) out[i] = rois[i];
}

// ---------------------------------------------------------------------------
// Launch
// ---------------------------------------------------------------------------
extern "C" void kernel_launch(void* const* d_in, const int* in_sizes, int n_in,
                              void* d_out, int out_size, void* d_ws,
                              size_t ws_size, hipStream_t stream) {
  const float* im = (const float*)d_in[0];
  const float* rois = (const float*)d_in[1];
  const float* w1 = (const float*)d_in[2];
  const float* b1 = (const float*)d_in[3];
  const float* w2 = (const float*)d_in[4];
  const float* b2 = (const float*)d_in[5];
  const float* w3 = (const float*)d_in[6];
  const float* b3 = (const float*)d_in[7];
  const float* w4 = (const float*)d_in[8];
  const float* b4 = (const float*)d_in[9];
  const float* fc6_w = (const float*)d_in[10];
  const float* fc6_b = (const float*)d_in[11];
  const float* fc7_w = (const float*)d_in[12];
  const float* fc7_b = (const float*)d_in[13];
  const float* cls_w = (const float*)d_in[14];
  const float* cls_b = (const float*)d_in[15];
  const float* bbox_w = (const float*)d_in[16];
  const float* bbox_b = (const float*)d_in[17];

  float* ws = (float*)d_ws;
  // layout (float offsets), total 24,576,000 floats = 98.3 MB:
  //   x1   @ 0          : 6,553,600   (64x320x320) -- overlaid later by
  //        pooledb @0 (3,763,200), h6b @3,763,200 (614,400),
  //        h7b @4,377,600 (614,400), cls_score @4,992,000 (24,300)
  //   x2   @ 6,553,600  : 3,276,800   (128x160x160)
  //   x3   @ 9,830,400  : 1,638,400   (256x80x80)
  //   x4   @ 11,468,800 :   819,200   (512x40x40)
  //   col  @ 12,288,000 : 7,372,800   (bf16: 14,745,600 ushorts, max conv2)
  //   cpart@ 19,660,800 : 4,915,200   (split-K partials, max fc S=4)
  float* x1 = ws;
  float* x2 = ws + 6553600;
  float* x3 = ws + 9830400;
  float* x4 = ws + 11468800;
  unsigned short* col = (unsigned short*)(ws + 12288000);
  float* cpart = ws + 19660800;
  unsigned short* pooledb = (unsigned short*)ws;
  unsigned short* h6b = (unsigned short*)(ws + 3763200);
  unsigned short* h7b = (unsigned short*)(ws + 4377600);
  float* cls_score = ws + 4992000;

  float* out = (float*)d_out;
  float* out_rois = out;          // 1500
  float* out_cls = out + 1500;    // 24300
  float* out_bbox = out + 25800;  // 97200

  // conv1: (3,640,640) -> (64,320,320), direct
  conv_s2_relu<3, 4><<<dim3(400, 16), 256, 0, stream>>>(im, w1, b1, x1, 640,
                                                        640, 320, 320);

  // conv2: im2col + GEMM  M=128 N=25600 K=576
  im2col_bf16<<<dim3(6400), 256, 0, stream>>>(x1, col, 64, 320, 320, 160, 160);
  gemm_mfma<false, true><<<dim3(200, 1, 1), 256, 0, stream>>>(
      w2, col, cpart, 128, 25600, 576, 576);
  finalize_kernel<<<dim3(12800), 256, 0, stream>>>(cpart, b2, x2, 128, 25600,
                                                   1, 0, 1, 0);

  // conv3: M=256 N=6400 K=1152, S=2
  im2col_bf16<<<dim3(3200), 256, 0, stream>>>(x2, col, 128, 160, 160, 80, 80);
  gemm_mfma<false, true><<<dim3(50, 2, 2), 256, 0, stream>>>(
      w3, col, cpart, 256, 6400, 1152, 576);
  finalize_kernel<<<dim3(6400), 256, 0, stream>>>(cpart, b3, x3, 256, 6400, 2,
                                                  0, 1, 0);

  // conv4: M=512 N=1600 K=2304, S=4
  im2col_bf16<<<dim3(1600), 256, 0, stream>>>(x3, col, 256, 80, 80, 40, 40);
  gemm_mfma<false, true><<<dim3(13, 4, 4), 256, 0, stream>>>(
      w4, col, cpart, 512, 1600, 2304, 576);
  finalize_kernel<<<dim3(3200), 256, 0, stream>>>(cpart, b4, x4, 512, 1600, 4,
                                                  0, 1, 0);

  // roi align -> bf16 pooled (300 x 25088)
  roi_align_kernel<<<dim3(29400), 256, 0, stream>>>(x4, rois, pooledb);

  // fc6: M=300 N=4096 K=25088, S=4 -> h6 (bf16, relu)
  gemm_mfma<true, false><<<dim3(32, 3, 4), 256, 0, stream>>>(
      pooledb, fc6_w, cpart, 300, 4096, 25088, 6272);
  finalize_kernel<<<dim3(4800), 256, 0, stream>>>(cpart, fc6_b, h6b, 300, 4096,
                                                  4, 1, 1, 1);

  // fc7: M=300 N=4096 K=4096, S=4 -> h7 (bf16, relu)
  gemm_mfma<true, false><<<dim3(32, 3, 4), 256, 0, stream>>>(
      h6b, fc7_w, cpart, 300, 4096, 4096, 1024);
  finalize_kernel<<<dim3(4800), 256, 0, stream>>>(cpart, fc7_b, h7b, 300, 4096,
                                                  4, 1, 1, 1);

  // cls head: M=300 N=81 K=4096, S=16 -> cls_score (fp32)
  gemm_mfma<true, false><<<dim3(1, 3, 16), 256, 0, stream>>>(
      h7b, cls_w, cpart, 300, 81, 4096, 256);
  finalize_kernel<<<dim3(95), 256, 0, stream>>>(cpart, cls_b, cls_score, 300,
                                                81, 16, 1, 0, 0);

  // bbox head: M=300 N=324 K=4096, S=16 -> out_bbox (fp32)
  gemm_mfma<true, false><<<dim3(3, 3, 16), 256, 0, stream>>>(
      h7b, bbox_w, cpart, 300, 324, 4096, 256);
  finalize_kernel<<<dim3(380), 256, 0, stream>>>(cpart, bbox_b, out_bbox, 300,
                                                 324, 16, 1, 0, 0);

  softmax81<<<dim3(3), 128, 0, stream>>>(cls_score, out_cls);
  copy_rois<<<dim3(6), 256, 0, stream>>>(rois, out_rois);
}